// Round 4
// baseline (427.241 us; speedup 1.0000x reference)
//
#include <hip/hip_runtime.h>
#include <math.h>

#define NN 16384
#define CAP 128   // per-query LDS candidate buffer (u64 keys)
#define WM 64     // shrink watermark; shrink inside push keeps cnt <= 127
#define KTOP 17   // keep top-17 (incl. self at dist~0), drop self at output
#define GRD 32    // grid cells per axis
#define GH 0.25f  // cell width over [-4,4]

typedef unsigned long long u64;

__device__ __forceinline__ int mbcnt64(u64 mask) {
  return __builtin_amdgcn_mbcnt_hi(
      (unsigned)(mask >> 32),
      __builtin_amdgcn_mbcnt_lo((unsigned)mask, 0));
}

// monotone float -> uint mapping (preserves total order incl. negatives)
__device__ __forceinline__ unsigned fmap(float d) {
  unsigned ub = __float_as_uint(d);
  return ub ^ ((unsigned)((int)ub >> 31) | 0x80000000u);
}

__device__ __forceinline__ float unfmap(unsigned ub) {
  unsigned fb = (ub & 0x80000000u) ? (ub ^ 0x80000000u) : ~ub;
  return __uint_as_float(fb);
}

// fp32 <-> bf16 (RNE, NaN-free data)
__device__ __forceinline__ unsigned short f2bf(float f) {
  unsigned u = __float_as_uint(f);
  return (unsigned short)((u + 0x7FFFu + ((u >> 16) & 1u)) >> 16);
}
__device__ __forceinline__ float bf2f(unsigned short h) {
  return __uint_as_float(((unsigned)h) << 16);
}

__device__ __forceinline__ u64 u64min(u64 a, u64 b) { return a < b ? a : b; }
__device__ __forceinline__ u64 u64max(u64 a, u64 b) { return a > b ? a : b; }

__device__ __forceinline__ int cellc(float v) {
  int c = (int)floorf((v + 4.0f) * 4.0f);
  return c < 0 ? 0 : (c > GRD - 1 ? GRD - 1 : c);
}

// bitonic sort of 64 u64 keys (1 reg/lane), ascending.
__device__ __forceinline__ void sort64(u64& r0, int lane) {
#pragma unroll
  for (int k = 2; k <= 64; k <<= 1) {
#pragma unroll
    for (int jj = k >> 1; jj >= 1; jj >>= 1) {
      const bool up = (lane & jj) == 0;
      const bool asc = (lane & k) == 0;
      u64 o = __shfl_xor(r0, jj);
      r0 = (up == asc) ? u64min(r0, o) : u64max(r0, o);
    }
  }
}

// radix-select shrink: find p = KTOP-th smallest mapped key among buf[0..cnt),
// keep all entries with key <= p (ties kept -> exactness), compact to front.
// Key domain fmap(-L), monotone in d for fixed query. cq = L_kth: keep L >= cq.
// Requires cnt >= KTOP. Wave-uniform call sites only.
__device__ __forceinline__ void radix_shrink(u64* buf, int& cnt, float& cq,
                                             int lane) {
  const u64 k0 = (lane < cnt) ? buf[lane] : ~0ull;
  const u64 k1 = (lane + 64 < cnt) ? buf[lane + 64] : ~0ull;
  const unsigned d0 = (unsigned)(k0 >> 32);
  const unsigned d1 = (unsigned)(k1 >> 32);
  unsigned p = 0u;
#pragma unroll
  for (int b = 31; b >= 0; --b) {
    const unsigned c = p | (1u << b);
    const u64 b0 = __ballot(d0 < c);
    const u64 b1 = __ballot(d1 < c);
    const int n = __popcll(b0) + __popcll(b1);
    if (n < KTOP) p = c;  // invariant: count(key < p) < KTOP
  }
  const bool v0 = d0 <= p;
  const bool v1 = d1 <= p;
  const u64 m0 = __ballot(v0);
  const u64 m1 = __ballot(v1);
  const int base = __popcll(m0);
  if (v0) buf[mbcnt64(m0)] = k0;
  if (v1) buf[base + mbcnt64(m1)] = k1;
  cnt = base + __popcll(m1);
  cq = -unfmap(p);
}

// ---------------- build phase: 32^3 cell grid, counting sort ----------------
// pack_cells: coords -> float4(x,y,z,-|p|^2/2), cell id, histogram
__global__ __launch_bounds__(256) void pack_cells(const float* __restrict__ x,
                                                  float4* __restrict__ tmp4,
                                                  int* __restrict__ cid,
                                                  unsigned* __restrict__ hist) {
  const int i = blockIdx.x * 256 + threadIdx.x;
  const float a = x[i * 64 + 0];
  const float b = x[i * 64 + 1];
  const float c = x[i * 64 + 2];
  tmp4[i] = make_float4(a, b, c, -0.5f * (a * a + b * b + c * c));
  const int cell = (cellc(c) * GRD + cellc(b)) * GRD + cellc(a);
  cid[i] = cell;
  atomicAdd(&hist[cell], 1u);
}

// prefix_cells: single block, 1024 threads x 32 cells each -> exclusive scan
__global__ __launch_bounds__(1024) void prefix_cells(
    const unsigned* __restrict__ hist, unsigned* __restrict__ cellstart,
    unsigned* __restrict__ cellfill) {
  __shared__ unsigned ls[1024];
  const int t = threadIdx.x;
  unsigned s = 0;
  for (int k = 0; k < 32; ++k) s += hist[t * 32 + k];
  ls[t] = s;
  __syncthreads();
  for (int off = 1; off < 1024; off <<= 1) {
    const unsigned v = (t >= off) ? ls[t - off] : 0u;
    __syncthreads();
    ls[t] += v;
    __syncthreads();
  }
  unsigned run = ls[t] - s;  // exclusive prefix
  for (int k = 0; k < 32; ++k) {
    cellstart[t * 32 + k] = run;
    cellfill[t * 32 + k] = run;
    run += hist[t * 32 + k];
  }
  if (t == 1023) cellstart[GRD * GRD * GRD] = run;  // = NN
}

// scatter_cells: counting-sort points into cell order
__global__ __launch_bounds__(256) void scatter_cells(
    const float4* __restrict__ tmp4, const int* __restrict__ cid,
    unsigned* __restrict__ cellfill, float4* __restrict__ sorted4,
    int* __restrict__ sidx) {
  const int i = blockIdx.x * 256 + threadIdx.x;
  const unsigned pos = atomicAdd(&cellfill[cid[i]], 1u);
  sorted4[pos] = tmp4[i];
  sidx[pos] = i;
}

// ---------------- kNN via adaptive cell-ball scan (r15) ----------------
// One wave per query (query = sorted position). Scan Chebyshev ball of cells
// ring by ring; x-contiguous cells merge into one coalesced run per (y,z)
// row. Exact stop: points in cells with index gap >= rho+1 are >= rho*h away
// (clamping only moves assigned cells inward -> bound stays a lower bound),
// so stop when (rho_done*h)^2 > d17. Hot test L >= cq as r14 (3 FMA + cmp);
// keys fmap(-L)<<32 | origIdx keep reference tie order; self dropped at out.
__global__ __launch_bounds__(256) void knn_grid(
    const float4* __restrict__ sorted4, const int* __restrict__ sidx,
    const unsigned* __restrict__ cellstart, int* __restrict__ src) {
  __shared__ u64 bufs_[4][CAP];  // 4 KB
  const int lane = threadIdx.x & 63;
  const int wid = threadIdx.x >> 6;
  u64* buf = bufs_[wid];
  const int qpos = blockIdx.x * 4 + wid;
  const float4 me = sorted4[qpos];
  const int qorig = sidx[qpos];
  const float qx = me.x, qy = me.y, qz = me.z;
  const float myq2 = -2.0f * me.w;  // |q|^2
  const int cx = cellc(qx), cy = cellc(qy), cz = cellc(qz);
  float cq = -INFINITY;
  int cnt = 0;

  auto scan_run = [&](int xa, int xb, int y, int z) {
    const int x0 = xa < 0 ? 0 : xa;
    const int x1 = xb > GRD - 1 ? GRD - 1 : xb;
    if (x0 > x1) return;
    const int c0 = (z * GRD + y) * GRD + x0;
    const int s = (int)cellstart[c0];
    const int e = (int)cellstart[c0 + (x1 - x0) + 1];
    for (int o = s; o < e; o += 64) {
      const int j = o + lane;
      const bool in = j < e;
      const float4 p = sorted4[in ? j : s];
      const float L = fmaf(qx, p.x, fmaf(qy, p.y, fmaf(qz, p.z, p.w)));
      const bool pass = in && (L >= cq);
      const u64 mk = __ballot(pass);
      if (mk) {  // wave-uniform
        if (pass)
          buf[cnt + mbcnt64(mk)] =
              ((u64)fmap(-L) << 32) | (unsigned)sidx[j];
        cnt += __popcll(mk);
        if (cnt >= WM) radix_shrink(buf, cnt, cq, lane);
      }
    }
  };

  int rho_done = -1;  // nothing scanned
  int rho_t = 1;
  while (true) {
    for (int dz = -rho_t; dz <= rho_t; ++dz) {
      const int z = cz + dz;
      if ((unsigned)z > (unsigned)(GRD - 1)) continue;
      const int adz = dz < 0 ? -dz : dz;
      for (int dy = -rho_t; dy <= rho_t; ++dy) {
        const int y = cy + dy;
        if ((unsigned)y > (unsigned)(GRD - 1)) continue;
        const int ady = dy < 0 ? -dy : dy;
        const int m = adz > ady ? adz : ady;
        if (m > rho_done) {  // new row: full x-span
          scan_run(cx - rho_t, cx + rho_t, y, z);
        } else {  // previously scanned row: x extensions only
          scan_run(cx - rho_t, cx - rho_done - 1, y, z);
          scan_run(cx + rho_done + 1, cx + rho_t, y, z);
        }
      }
    }
    rho_done = rho_t;
    if (cnt >= KTOP) {
      radix_shrink(buf, cnt, cq, lane);  // exact kth -> d17, compact
      const float d17 = fmaxf(myq2 - 2.0f * cq, 0.0f);
      const float need = sqrtf(d17 * 1.000002f + 1e-12f) * (1.0f / GH);
      if ((float)rho_done >= need || rho_done >= GRD) break;
      int rn = (int)need + 1;
      rho_t = rn > rho_done + 1 ? rn : rho_done + 1;
      if (rho_t > GRD) rho_t = GRD;
    } else {
      rho_t = rho_done + 1;  // can't exceed GRD: full grid has >= KTOP pts
    }
  }

  // final: exact (key, idx)-sorted top-17 via one 64-wide bitonic sort
  u64 r0 = (lane < cnt) ? buf[lane] : ~0ull;
  sort64(r0, lane);
  const int idx = (int)(r0 & 0xFFFFFFFFull);
  const u64 selfm = __ballot((lane < KTOP) && (idx == qorig));
  const int sp = selfm ? (__ffsll((long long)selfm) - 1) : 99;
  const int outrank = lane - (lane > sp ? 1 : 0);
  if (lane < KTOP && lane != sp && outrank < 16)
    src[qorig * 16 + outrank] = idx;
}

// ---------------- fused q|k|v|s GEMM: [N,KD] x 4x[KD,128] ----------
// q,s -> fp32 qs[node][256] (q: 0..127, s: 128..255)
// k,v -> bf16 kvh[node][256] (k: 0..127, v: 128..255) -- halves attn gathers
template <int KD>
__global__ __launch_bounds__(256) void gemm_qkvs(
    const float* __restrict__ X, const float* __restrict__ W0,
    const float* __restrict__ W1, const float* __restrict__ W2,
    const float* __restrict__ W3, const float* __restrict__ B0,
    const float* __restrict__ B1, const float* __restrict__ B2,
    const float* __restrict__ B3, float* __restrict__ qs,
    unsigned short* __restrict__ kvh) {
  __shared__ float As[64][68];  // [k][row], padded k-stride 68
  __shared__ float Bs[64][64];  // [k][col]
  const int brow = blockIdx.x * 64;
  const int by = blockIdx.y;          // 0..7 -> (matrix, half)
  const int wi = by >> 1;
  const float* W = wi == 0 ? W0 : wi == 1 ? W1 : wi == 2 ? W2 : W3;
  const float* bias = wi == 0 ? B0 : wi == 1 ? B1 : wi == 2 ? B2 : B3;
  const int cbase = (by & 1) * 64;
  const int tx = threadIdx.x & 15;   // col group (4 cols)
  const int ty = threadIdx.x >> 4;   // row group (4 rows)

  float acc[4][4] = {};
  for (int k0 = 0; k0 < KD; k0 += 64) {
    __syncthreads();
#pragma unroll
    for (int i = 0; i < 4; ++i) {  // stage A transposed: 64 rows x 64 k
      const int flat = threadIdx.x * 4 + i * 1024;
      const int r = flat >> 6, kk = flat & 63;
      const float4 v = *(const float4*)&X[(brow + r) * KD + k0 + kk];
      As[kk + 0][r] = v.x;
      As[kk + 1][r] = v.y;
      As[kk + 2][r] = v.z;
      As[kk + 3][r] = v.w;
    }
#pragma unroll
    for (int i = 0; i < 4; ++i) {  // stage B: 64 k x 64 cols
      const int flat = threadIdx.x * 4 + i * 1024;
      const int kk = flat >> 6, c = flat & 63;
      *(float4*)&Bs[kk][c] = *(const float4*)&W[(k0 + kk) * 128 + cbase + c];
    }
    __syncthreads();
#pragma unroll 8
    for (int k = 0; k < 64; ++k) {
      const float4 a = *(const float4*)&As[k][ty * 4];
      const float4 b = *(const float4*)&Bs[k][tx * 4];
      const float av[4] = {a.x, a.y, a.z, a.w};
      const float bv[4] = {b.x, b.y, b.z, b.w};
#pragma unroll
      for (int i = 0; i < 4; ++i)
#pragma unroll
        for (int jj = 0; jj < 4; ++jj)
          acc[i][jj] = fmaf(av[i], bv[jj], acc[i][jj]);
    }
  }
  const float4 bi = *(const float4*)&bias[cbase + tx * 4];
  const int col = cbase + tx * 4;
#pragma unroll
  for (int i = 0; i < 4; ++i) {
    const int row = brow + ty * 4 + i;
    float4 o;
    o.x = acc[i][0] + bi.x;
    o.y = acc[i][1] + bi.y;
    o.z = acc[i][2] + bi.z;
    o.w = acc[i][3] + bi.w;
    if (wi == 0) {
      *(float4*)&qs[row * 256 + col] = o;
    } else if (wi == 3) {
      *(float4*)&qs[row * 256 + 128 + col] = o;
    } else {
      ushort4 h;
      h.x = f2bf(o.x);
      h.y = f2bf(o.y);
      h.z = f2bf(o.z);
      h.w = f2bf(o.w);
      *(ushort4*)&kvh[row * 256 + (wi == 1 ? col : 128 + col)] = h;
    }
  }
}

// ---------------- attention, c=128: 32-lane group per node ----
__global__ __launch_bounds__(256) void attn_c128(
    const float* __restrict__ qs, const unsigned short* __restrict__ kvh,
    const int* __restrict__ src, const float* __restrict__ res,
    float* __restrict__ hout, int do_res) {
  const int g = threadIdx.x >> 5;  // 8 groups of 32 lanes per block
  const int node = blockIdx.x * 8 + g;
  const int c = threadIdx.x & 31;
  const float4 q4 = ((const float4*)(qs + node * 256))[c];

  int nb[16];
#pragma unroll
  for (int r = 0; r < 16; ++r) nb[r] = src[node * 16 + r];

  float p[16];
#pragma unroll
  for (int r = 0; r < 16; ++r) {
    const ushort4 k4 = ((const ushort4*)(kvh + nb[r] * 256))[c];
    p[r] = q4.x * bf2f(k4.x) + q4.y * bf2f(k4.y) + q4.z * bf2f(k4.z) +
           q4.w * bf2f(k4.w);
  }
#pragma unroll
  for (int o = 16; o; o >>= 1) {  // group-local (xor offsets < 32)
#pragma unroll
    for (int r = 0; r < 16; ++r) p[r] += __shfl_xor(p[r], o);
  }

  float m = p[0];
#pragma unroll
  for (int r = 1; r < 16; ++r) m = fmaxf(m, p[r]);
  float w[16];
  float den = 0.0f;
#pragma unroll
  for (int r = 0; r < 16; ++r) {
    w[r] = __expf((p[r] - m) * 0.088388347648318447f);  // 1/sqrt(128)
    den += w[r];
  }
  const float inv = 1.0f / den;
  float o0 = 0.0f, o1 = 0.0f, o2 = 0.0f, o3 = 0.0f;
#pragma unroll
  for (int r = 0; r < 16; ++r) {
    const ushort4 v4 = ((const ushort4*)(kvh + nb[r] * 256 + 128))[c];
    const float ww = w[r] * inv;
    o0 = fmaf(ww, bf2f(v4.x), o0);
    o1 = fmaf(ww, bf2f(v4.y), o1);
    o2 = fmaf(ww, bf2f(v4.z), o2);
    o3 = fmaf(ww, bf2f(v4.w), o3);
  }
  const float4 s4 = ((const float4*)(qs + node * 256 + 128))[c];
  float r0 = o0 + s4.x, r1 = o1 + s4.y, r2 = o2 + s4.z, r3 = o3 + s4.w;
  if (do_res) {
    const float4 h4 = ((const float4*)(res + node * 128))[c];
    r0 += h4.x;
    r1 += h4.y;
    r2 += h4.z;
    r3 += h4.w;
  }
  ((float4*)(hout + node * 128))[c] =
      make_float4(tanhf(r0), tanhf(r1), tanhf(r2), tanhf(r3));
}

// ---------------- layer 3 GEMM: [N,128] x 4x[128,3] -> [N,12] ----------------
__global__ __launch_bounds__(256) void gemm_qkvs3(
    const float* __restrict__ H, const float* __restrict__ W0,
    const float* __restrict__ W1, const float* __restrict__ W2,
    const float* __restrict__ W3, const float* __restrict__ B0,
    const float* __restrict__ B1, const float* __restrict__ B2,
    const float* __restrict__ B3, float* __restrict__ out) {
  __shared__ float hs[64][132];
  __shared__ float wsh[128 * 12];
  __shared__ float bsh[12];
  const int brow = blockIdx.x * 64;
  if (threadIdx.x < 12) {
    const int mi = threadIdx.x / 3, c = threadIdx.x % 3;
    const float* Bsel = mi == 0 ? B0 : mi == 1 ? B1 : mi == 2 ? B2 : B3;
    bsh[threadIdx.x] = Bsel[c];
  }
  for (int t = threadIdx.x; t < 1536; t += 256) {
    const int k = t / 12, cc = t % 12;
    const int mi = cc / 3, c = cc % 3;
    const float* Wsel = mi == 0 ? W0 : mi == 1 ? W1 : mi == 2 ? W2 : W3;
    wsh[t] = Wsel[k * 3 + c];
  }
#pragma unroll
  for (int i = 0; i < 8; ++i) {
    const int flat = threadIdx.x * 4 + i * 1024;
    const int r = flat >> 7, kk = flat & 127;
    *(float4*)&hs[r][kk] = *(const float4*)&H[(brow + r) * 128 + kk];
  }
  __syncthreads();
  const int r = threadIdx.x >> 2;
  const int part = threadIdx.x & 3;
  float a0 = 0.0f, a1 = 0.0f, a2 = 0.0f;
#pragma unroll 4
  for (int k = 0; k < 128; ++k) {
    const float h = hs[r][k];
    a0 = fmaf(h, wsh[k * 12 + part * 3 + 0], a0);
    a1 = fmaf(h, wsh[k * 12 + part * 3 + 1], a1);
    a2 = fmaf(h, wsh[k * 12 + part * 3 + 2], a2);
  }
  const int row = brow + r;
  out[row * 12 + part * 3 + 0] = a0 + bsh[part * 3 + 0];
  out[row * 12 + part * 3 + 1] = a1 + bsh[part * 3 + 1];
  out[row * 12 + part * 3 + 2] = a2 + bsh[part * 3 + 2];
}

// ---------------- attention, c=3: 16 lanes per node ----------------
__global__ __launch_bounds__(256) void attn_c3(const float* __restrict__ q3,
                                               const int* __restrict__ src,
                                               float* __restrict__ out) {
  const int gid = blockIdx.x * 256 + threadIdx.x;
  const int node = gid >> 4, r = gid & 15;
  const int j = src[node * 16 + r];
  const float* qn = q3 + node * 12;
  const float* kj = q3 + j * 12 + 3;
  float alpha = (qn[0] * kj[0] + qn[1] * kj[1] + qn[2] * kj[2]) *
                0.57735026918962576f;  // 1/sqrt(3)
  float m = alpha;
#pragma unroll
  for (int o = 8; o; o >>= 1) m = fmaxf(m, __shfl_xor(m, o, 16));
  const float e = __expf(alpha - m);
  float den = e;
#pragma unroll
  for (int o = 8; o; o >>= 1) den += __shfl_xor(den, o, 16);
  const float wgt = e / den;
  const float* vj = q3 + j * 12 + 6;
  float o0 = wgt * vj[0], o1 = wgt * vj[1], o2 = wgt * vj[2];
#pragma unroll
  for (int o = 8; o; o >>= 1) {
    o0 += __shfl_xor(o0, o, 16);
    o1 += __shfl_xor(o1, o, 16);
    o2 += __shfl_xor(o2, o, 16);
  }
  if (r == 0) {
    const float* sn = q3 + node * 12 + 9;
    out[node * 3 + 0] = o0 + sn[0];
    out[node * 3 + 1] = o1 + sn[1];
    out[node * 3 + 2] = o2 + sn[2];
  }
}

extern "C" void kernel_launch(void* const* d_in, const int* in_sizes, int n_in,
                              void* d_out, int out_size, void* d_ws,
                              size_t ws_size, hipStream_t stream) {
  const float* x = (const float*)d_in[1];
  const float* Wq1 = (const float*)d_in[2];
  const float* bq1 = (const float*)d_in[3];
  const float* Wk1 = (const float*)d_in[4];
  const float* bk1 = (const float*)d_in[5];
  const float* Wv1 = (const float*)d_in[6];
  const float* bv1 = (const float*)d_in[7];
  const float* Ws1 = (const float*)d_in[8];
  const float* bs1 = (const float*)d_in[9];
  const float* Wq2 = (const float*)d_in[10];
  const float* bq2 = (const float*)d_in[11];
  const float* Wk2 = (const float*)d_in[12];
  const float* bk2 = (const float*)d_in[13];
  const float* Wv2 = (const float*)d_in[14];
  const float* bv2 = (const float*)d_in[15];
  const float* Ws2 = (const float*)d_in[16];
  const float* bs2 = (const float*)d_in[17];
  const float* Wq3 = (const float*)d_in[18];
  const float* bq3 = (const float*)d_in[19];
  const float* Wk3 = (const float*)d_in[20];
  const float* bk3 = (const float*)d_in[21];
  const float* Wv3 = (const float*)d_in[22];
  const float* bv3 = (const float*)d_in[23];
  const float* Ws3 = (const float*)d_in[24];
  const float* bs3 = (const float*)d_in[25];

  const size_t MB = 1024 * 1024;
  const size_t KB = 1024;
  char* ws = (char*)d_ws;
  // knn build temporaries live in the qs region [0,16MB): dead until gemm1,
  // which runs strictly after knn_grid on the same stream.
  float4* tmp4 = (float4*)(ws);                           // 256 KB
  float4* sorted4 = (float4*)(ws + 256 * KB);             // 256 KB
  int* cid = (int*)(ws + 512 * KB);                       // 64 KB
  int* sidx = (int*)(ws + 576 * KB);                      // 64 KB
  unsigned* hist = (unsigned*)(ws + 640 * KB);            // 128 KB
  unsigned* cellstart = (unsigned*)(ws + 768 * KB);       // 128 KB + 4
  unsigned* cellfill = (unsigned*)(ws + 904 * KB);        // 128 KB

  float* qs = (float*)(ws);                               // 16 MB (q|s fp32)
  unsigned short* kvh = (unsigned short*)(ws + 16 * MB);  // 8 MB (k|v bf16)
  float* h1 = (float*)(ws + 24 * MB);                     // 8 MB
  float* h2 = (float*)(ws + 32 * MB);                     // 8 MB
  int* src = (int*)(ws + 40 * MB);                        // 1 MB
  float* q3 = (float*)(ws + 42 * MB);                     // 768 KB
  float* out = (float*)d_out;

  hipMemsetAsync(hist, 0, GRD * GRD * GRD * sizeof(unsigned), stream);
  pack_cells<<<NN / 256, 256, 0, stream>>>(x, tmp4, cid, hist);
  prefix_cells<<<1, 1024, 0, stream>>>(hist, cellstart, cellfill);
  scatter_cells<<<NN / 256, 256, 0, stream>>>(tmp4, cid, cellfill, sorted4,
                                              sidx);
  knn_grid<<<NN / 4, 256, 0, stream>>>(sorted4, sidx, cellstart, src);
  gemm_qkvs<64><<<dim3(NN / 64, 8), 256, 0, stream>>>(
      x, Wq1, Wk1, Wv1, Ws1, bq1, bk1, bv1, bs1, qs, kvh);
  attn_c128<<<NN / 8, 256, 0, stream>>>(qs, kvh, src, nullptr, h1, 0);
  gemm_qkvs<128><<<dim3(NN / 64, 8), 256, 0, stream>>>(
      h1, Wq2, Wk2, Wv2, Ws2, bq2, bk2, bv2, bs2, qs, kvh);
  attn_c128<<<NN / 8, 256, 0, stream>>>(qs, kvh, src, h1, h2, 1);
  gemm_qkvs3<<<NN / 64, 256, 0, stream>>>(h2, Wq3, Wk3, Wv3, Ws3, bq3, bk3,
                                          bv3, bs3, q3);
  attn_c3<<<NN * 16 / 256, 256, 0, stream>>>(q3, src, out);
}

// Round 5
// 363.246 us; speedup vs baseline: 1.1762x; 1.1762x over previous
//
#include <hip/hip_runtime.h>
#include <math.h>

#define NN 16384
#define CAP 128    // per-query LDS candidate buffer (u64 keys)
#define WM 64      // shrink watermark; shrink inside push keeps cnt <= 127
#define KTOP 17    // keep top-17 (incl. self at dist~0), drop self at output
#define NSLAB 128  // z-slabs over [-4,4]
#define SH 0.0625f // slab width
#define SHI 16.0f  // 1/SH

typedef unsigned long long u64;

__device__ __forceinline__ int mbcnt64(u64 mask) {
  return __builtin_amdgcn_mbcnt_hi(
      (unsigned)(mask >> 32),
      __builtin_amdgcn_mbcnt_lo((unsigned)mask, 0));
}

// monotone float -> uint mapping (preserves total order incl. negatives)
__device__ __forceinline__ unsigned fmap(float d) {
  unsigned ub = __float_as_uint(d);
  return ub ^ ((unsigned)((int)ub >> 31) | 0x80000000u);
}

__device__ __forceinline__ float unfmap(unsigned ub) {
  unsigned fb = (ub & 0x80000000u) ? (ub ^ 0x80000000u) : ~ub;
  return __uint_as_float(fb);
}

// fp32 <-> bf16 (RNE, NaN-free data)
__device__ __forceinline__ unsigned short f2bf(float f) {
  unsigned u = __float_as_uint(f);
  return (unsigned short)((u + 0x7FFFu + ((u >> 16) & 1u)) >> 16);
}
__device__ __forceinline__ float bf2f(unsigned short h) {
  return __uint_as_float(((unsigned)h) << 16);
}

__device__ __forceinline__ u64 u64min(u64 a, u64 b) { return a < b ? a : b; }
__device__ __forceinline__ u64 u64max(u64 a, u64 b) { return a > b ? a : b; }

__device__ __forceinline__ int slabof(float v) {
  int c = (int)floorf((v + 4.0f) * SHI);
  return c < 0 ? 0 : (c > NSLAB - 1 ? NSLAB - 1 : c);
}

// bitonic sort of 64 u64 keys (1 reg/lane), ascending. cnt <= 63 at loop exit
// (push handler shrinks whenever cnt >= WM=64), so 64 slots suffice.
__device__ __forceinline__ void sort64(u64& r0, int lane) {
#pragma unroll
  for (int k = 2; k <= 64; k <<= 1) {
#pragma unroll
    for (int jj = k >> 1; jj >= 1; jj >>= 1) {
      const bool up = (lane & jj) == 0;
      const bool asc = (lane & k) == 0;
      u64 o = __shfl_xor(r0, jj);
      r0 = (up == asc) ? u64min(r0, o) : u64max(r0, o);
    }
  }
}

// radix-select shrink: p = KTOP-th smallest mapped key among buf[0..cnt),
// keep all entries with key <= p (ties kept -> exactness), compact to front.
// Key domain fmap(-L), monotone in d for fixed query. cq = L_kth: keep L >= cq.
__device__ __forceinline__ void radix_shrink(u64* buf, int& cnt, float& cq,
                                             int lane) {
  const u64 k0 = (lane < cnt) ? buf[lane] : ~0ull;
  const u64 k1 = (lane + 64 < cnt) ? buf[lane + 64] : ~0ull;
  const unsigned d0 = (unsigned)(k0 >> 32);
  const unsigned d1 = (unsigned)(k1 >> 32);
  unsigned p = 0u;
#pragma unroll
  for (int b = 31; b >= 0; --b) {
    const unsigned c = p | (1u << b);
    const u64 b0 = __ballot(d0 < c);
    const u64 b1 = __ballot(d1 < c);
    const int n = __popcll(b0) + __popcll(b1);
    if (n < KTOP) p = c;  // invariant: count(key < p) < KTOP
  }
  const bool v0 = d0 <= p;
  const bool v1 = d1 <= p;
  const u64 m0 = __ballot(v0);
  const u64 m1 = __ballot(v1);
  const int base = __popcll(m0);
  if (v0) buf[mbcnt64(m0)] = k0;
  if (v1) buf[base + mbcnt64(m1)] = k1;
  cnt = base + __popcll(m1);
  cq = -unfmap(p);
}

// ---------------- build: 128 z-slab counting sort ----------------
__global__ __launch_bounds__(256) void pack_slabs(const float* __restrict__ x,
                                                  float4* __restrict__ tmp4,
                                                  int* __restrict__ sid,
                                                  unsigned* __restrict__ hist) {
  const int i = blockIdx.x * 256 + threadIdx.x;
  const float a = x[i * 64 + 0];
  const float b = x[i * 64 + 1];
  const float c = x[i * 64 + 2];
  tmp4[i] = make_float4(a, b, c, -0.5f * (a * a + b * b + c * c));
  const int s = slabof(c);
  sid[i] = s;
  atomicAdd(&hist[s], 1u);
}

__global__ __launch_bounds__(128) void prefix_slabs(
    const unsigned* __restrict__ hist, unsigned* __restrict__ slabstart,
    unsigned* __restrict__ slabfill) {
  __shared__ unsigned ls[NSLAB];
  const int t = threadIdx.x;
  const unsigned h = hist[t];
  ls[t] = h;
  __syncthreads();
  for (int off = 1; off < NSLAB; off <<= 1) {
    const unsigned v = (t >= off) ? ls[t - off] : 0u;
    __syncthreads();
    ls[t] += v;
    __syncthreads();
  }
  const unsigned ex = ls[t] - h;  // exclusive
  slabstart[t] = ex;
  slabfill[t] = ex;
  if (t == NSLAB - 1) slabstart[NSLAB] = ls[t];  // = NN
}

__global__ __launch_bounds__(256) void scatter_slabs(
    const float4* __restrict__ tmp4, const int* __restrict__ sid,
    unsigned* __restrict__ slabfill, float4* __restrict__ sorted4,
    int* __restrict__ sidx) {
  const int i = blockIdx.x * 256 + threadIdx.x;
  const unsigned pos = atomicAdd(&slabfill[sid[i]], 1u);
  sorted4[pos] = tmp4[i];
  sidx[pos] = i;
}

// ---------------- kNN via z-slab window scan (r16) ----------------
// One wave per query (sorted position). Scan slabs outward nearest-first;
// stop a direction when (z-gap)^2 > d17 (slab spans are valid z lower
// bounds even under clamping). Inner loop = the PROVEN brute-force step:
// contiguous 64-cand float4 runs, test L >= cq (3 FMA + cmp), ballot push,
// radix shrink at WM. 1-deep prefetch inside runs hides load latency.
// Keys fmap(-L)<<32|origIdx -> exact, reference tie order; self dropped.
__global__ __launch_bounds__(256) void knn_z(
    const float4* __restrict__ sorted4, const int* __restrict__ sidx,
    const unsigned* __restrict__ slabstart, int* __restrict__ src) {
  __shared__ u64 bufs_[4][CAP];  // 4 KB
  const int lane = threadIdx.x & 63;
  const int wid = threadIdx.x >> 6;
  u64* buf = bufs_[wid];
  const int qpos = blockIdx.x * 4 + wid;
  const float4 me = sorted4[qpos];
  const int qorig = sidx[qpos];
  const float qx = me.x, qy = me.y, qz = me.z;
  const float q2 = -2.0f * me.w;  // |q|^2
  float cq = -INFINITY;
  int cnt = 0;

  auto scan_run = [&](int s, int e) {
    if (s >= e) return;
    int o = s;
    int j = o + lane;
    float4 p = sorted4[j < e ? j : s];
    while (o < e) {
      const int on = o + 64;
      float4 pn;
      if (on < e) {  // wave-uniform prefetch of next chunk
        const int jn = on + lane;
        pn = sorted4[jn < e ? jn : s];
      }
      const float L = fmaf(qx, p.x, fmaf(qy, p.y, fmaf(qz, p.z, p.w)));
      const bool pass = (j < e) && (L >= cq);
      const u64 mk = __ballot(pass);
      if (mk) {  // wave-uniform
        if (pass)
          buf[cnt + mbcnt64(mk)] = ((u64)fmap(-L) << 32) | (unsigned)sidx[j];
        cnt += __popcll(mk);
        if (cnt >= WM) radix_shrink(buf, cnt, cq, lane);
      }
      o = on;
      j = on + lane;
      p = pn;
    }
  };

  const int sq = slabof(qz);
  int su = sq, sd = sq - 1;
  bool up_done = false, dn_done = false;
  while (true) {
    bool can_up = !up_done && su <= NSLAB - 1;
    bool can_dn = !dn_done && sd >= 0;
    float bu = can_up ? fmaxf((-4.0f + su * SH) - qz, 0.0f) : 0.0f;
    float bd = can_dn ? fmaxf(qz - (-4.0f + (sd + 1) * SH), 0.0f) : 0.0f;
    if (cq != -INFINITY) {  // have a valid d17 after first shrink
      const float d17m =
          fmaxf(fmaf(-2.0f, cq, q2), 0.0f) * 1.00002f + 1e-4f;  // slack
      if (can_up && bu * bu > d17m) { can_up = false; up_done = true; }
      if (can_dn && bd * bd > d17m) { can_dn = false; dn_done = true; }
    }
    if (!can_up && !can_dn) {
      if (up_done && dn_done) break;
      if (su > NSLAB - 1 && sd < 0) break;
      // one side exhausted by range, other terminated -> break too
      if ((up_done || su > NSLAB - 1) && (dn_done || sd < 0)) break;
      // shouldn't reach here, but be safe:
      break;
    }
    if (can_up && (!can_dn || bu <= bd)) {
      scan_run((int)slabstart[su], (int)slabstart[su + 1]);
      ++su;
    } else {
      scan_run((int)slabstart[sd], (int)slabstart[sd + 1]);
      --sd;
    }
  }

  // final: exact (key, idx)-sorted top-17 via one 64-wide bitonic sort
  u64 r0 = (lane < cnt) ? buf[lane] : ~0ull;
  sort64(r0, lane);
  const int idx = (int)(r0 & 0xFFFFFFFFull);
  const u64 selfm = __ballot((lane < KTOP) && (idx == qorig));
  const int sp = selfm ? (__ffsll((long long)selfm) - 1) : 99;
  const int outrank = lane - (lane > sp ? 1 : 0);
  if (lane < KTOP && lane != sp && outrank < 16)
    src[qorig * 16 + outrank] = idx;
}

// ---------------- fused q|k|v|s GEMM: [N,KD] x 4x[KD,128] ----------
// q,s -> fp32 qs[node][256] (q: 0..127, s: 128..255)
// k,v -> bf16 kvh[node][256] (k: 0..127, v: 128..255) -- halves attn gathers
template <int KD>
__global__ __launch_bounds__(256) void gemm_qkvs(
    const float* __restrict__ X, const float* __restrict__ W0,
    const float* __restrict__ W1, const float* __restrict__ W2,
    const float* __restrict__ W3, const float* __restrict__ B0,
    const float* __restrict__ B1, const float* __restrict__ B2,
    const float* __restrict__ B3, float* __restrict__ qs,
    unsigned short* __restrict__ kvh) {
  __shared__ float As[64][68];  // [k][row], padded k-stride 68
  __shared__ float Bs[64][64];  // [k][col]
  const int brow = blockIdx.x * 64;
  const int by = blockIdx.y;          // 0..7 -> (matrix, half)
  const int wi = by >> 1;
  const float* W = wi == 0 ? W0 : wi == 1 ? W1 : wi == 2 ? W2 : W3;
  const float* bias = wi == 0 ? B0 : wi == 1 ? B1 : wi == 2 ? B2 : B3;
  const int cbase = (by & 1) * 64;
  const int tx = threadIdx.x & 15;   // col group (4 cols)
  const int ty = threadIdx.x >> 4;   // row group (4 rows)

  float acc[4][4] = {};
  for (int k0 = 0; k0 < KD; k0 += 64) {
    __syncthreads();
#pragma unroll
    for (int i = 0; i < 4; ++i) {  // stage A transposed: 64 rows x 64 k
      const int flat = threadIdx.x * 4 + i * 1024;
      const int r = flat >> 6, kk = flat & 63;
      const float4 v = *(const float4*)&X[(brow + r) * KD + k0 + kk];
      As[kk + 0][r] = v.x;
      As[kk + 1][r] = v.y;
      As[kk + 2][r] = v.z;
      As[kk + 3][r] = v.w;
    }
#pragma unroll
    for (int i = 0; i < 4; ++i) {  // stage B: 64 k x 64 cols
      const int flat = threadIdx.x * 4 + i * 1024;
      const int kk = flat >> 6, c = flat & 63;
      *(float4*)&Bs[kk][c] = *(const float4*)&W[(k0 + kk) * 128 + cbase + c];
    }
    __syncthreads();
#pragma unroll 8
    for (int k = 0; k < 64; ++k) {
      const float4 a = *(const float4*)&As[k][ty * 4];
      const float4 b = *(const float4*)&Bs[k][tx * 4];
      const float av[4] = {a.x, a.y, a.z, a.w};
      const float bv[4] = {b.x, b.y, b.z, b.w};
#pragma unroll
      for (int i = 0; i < 4; ++i)
#pragma unroll
        for (int jj = 0; jj < 4; ++jj)
          acc[i][jj] = fmaf(av[i], bv[jj], acc[i][jj]);
    }
  }
  const float4 bi = *(const float4*)&bias[cbase + tx * 4];
  const int col = cbase + tx * 4;
#pragma unroll
  for (int i = 0; i < 4; ++i) {
    const int row = brow + ty * 4 + i;
    float4 o;
    o.x = acc[i][0] + bi.x;
    o.y = acc[i][1] + bi.y;
    o.z = acc[i][2] + bi.z;
    o.w = acc[i][3] + bi.w;
    if (wi == 0) {
      *(float4*)&qs[row * 256 + col] = o;
    } else if (wi == 3) {
      *(float4*)&qs[row * 256 + 128 + col] = o;
    } else {
      ushort4 h;
      h.x = f2bf(o.x);
      h.y = f2bf(o.y);
      h.z = f2bf(o.z);
      h.w = f2bf(o.w);
      *(ushort4*)&kvh[row * 256 + (wi == 1 ? col : 128 + col)] = h;
    }
  }
}

// ---------------- attention, c=128: 32-lane group per node ----
__global__ __launch_bounds__(256) void attn_c128(
    const float* __restrict__ qs, const unsigned short* __restrict__ kvh,
    const int* __restrict__ src, const float* __restrict__ res,
    float* __restrict__ hout, int do_res) {
  const int g = threadIdx.x >> 5;  // 8 groups of 32 lanes per block
  const int node = blockIdx.x * 8 + g;
  const int c = threadIdx.x & 31;
  const float4 q4 = ((const float4*)(qs + node * 256))[c];

  int nb[16];
#pragma unroll
  for (int r = 0; r < 16; ++r) nb[r] = src[node * 16 + r];

  float p[16];
#pragma unroll
  for (int r = 0; r < 16; ++r) {
    const ushort4 k4 = ((const ushort4*)(kvh + nb[r] * 256))[c];
    p[r] = q4.x * bf2f(k4.x) + q4.y * bf2f(k4.y) + q4.z * bf2f(k4.z) +
           q4.w * bf2f(k4.w);
  }
#pragma unroll
  for (int o = 16; o; o >>= 1) {  // group-local (xor offsets < 32)
#pragma unroll
    for (int r = 0; r < 16; ++r) p[r] += __shfl_xor(p[r], o);
  }

  float m = p[0];
#pragma unroll
  for (int r = 1; r < 16; ++r) m = fmaxf(m, p[r]);
  float w[16];
  float den = 0.0f;
#pragma unroll
  for (int r = 0; r < 16; ++r) {
    w[r] = __expf((p[r] - m) * 0.088388347648318447f);  // 1/sqrt(128)
    den += w[r];
  }
  const float inv = 1.0f / den;
  float o0 = 0.0f, o1 = 0.0f, o2 = 0.0f, o3 = 0.0f;
#pragma unroll
  for (int r = 0; r < 16; ++r) {
    const ushort4 v4 = ((const ushort4*)(kvh + nb[r] * 256 + 128))[c];
    const float ww = w[r] * inv;
    o0 = fmaf(ww, bf2f(v4.x), o0);
    o1 = fmaf(ww, bf2f(v4.y), o1);
    o2 = fmaf(ww, bf2f(v4.z), o2);
    o3 = fmaf(ww, bf2f(v4.w), o3);
  }
  const float4 s4 = ((const float4*)(qs + node * 256 + 128))[c];
  float r0 = o0 + s4.x, r1 = o1 + s4.y, r2 = o2 + s4.z, r3 = o3 + s4.w;
  if (do_res) {
    const float4 h4 = ((const float4*)(res + node * 128))[c];
    r0 += h4.x;
    r1 += h4.y;
    r2 += h4.z;
    r3 += h4.w;
  }
  ((float4*)(hout + node * 128))[c] =
      make_float4(tanhf(r0), tanhf(r1), tanhf(r2), tanhf(r3));
}

// ---------------- layer 3 GEMM: [N,128] x 4x[128,3] -> [N,12] ----------------
__global__ __launch_bounds__(256) void gemm_qkvs3(
    const float* __restrict__ H, const float* __restrict__ W0,
    const float* __restrict__ W1, const float* __restrict__ W2,
    const float* __restrict__ W3, const float* __restrict__ B0,
    const float* __restrict__ B1, const float* __restrict__ B2,
    const float* __restrict__ B3, float* __restrict__ out) {
  __shared__ float hs[64][132];
  __shared__ float wsh[128 * 12];
  __shared__ float bsh[12];
  const int brow = blockIdx.x * 64;
  if (threadIdx.x < 12) {
    const int mi = threadIdx.x / 3, c = threadIdx.x % 3;
    const float* Bsel = mi == 0 ? B0 : mi == 1 ? B1 : mi == 2 ? B2 : B3;
    bsh[threadIdx.x] = Bsel[c];
  }
  for (int t = threadIdx.x; t < 1536; t += 256) {
    const int k = t / 12, cc = t % 12;
    const int mi = cc / 3, c = cc % 3;
    const float* Wsel = mi == 0 ? W0 : mi == 1 ? W1 : mi == 2 ? W2 : W3;
    wsh[t] = Wsel[k * 3 + c];
  }
#pragma unroll
  for (int i = 0; i < 8; ++i) {
    const int flat = threadIdx.x * 4 + i * 1024;
    const int r = flat >> 7, kk = flat & 127;
    *(float4*)&hs[r][kk] = *(const float4*)&H[(brow + r) * 128 + kk];
  }
  __syncthreads();
  const int r = threadIdx.x >> 2;
  const int part = threadIdx.x & 3;
  float a0 = 0.0f, a1 = 0.0f, a2 = 0.0f;
#pragma unroll 4
  for (int k = 0; k < 128; ++k) {
    const float h = hs[r][k];
    a0 = fmaf(h, wsh[k * 12 + part * 3 + 0], a0);
    a1 = fmaf(h, wsh[k * 12 + part * 3 + 1], a1);
    a2 = fmaf(h, wsh[k * 12 + part * 3 + 2], a2);
  }
  const int row = brow + r;
  out[row * 12 + part * 3 + 0] = a0 + bsh[part * 3 + 0];
  out[row * 12 + part * 3 + 1] = a1 + bsh[part * 3 + 1];
  out[row * 12 + part * 3 + 2] = a2 + bsh[part * 3 + 2];
}

// ---------------- attention, c=3: 16 lanes per node ----------------
__global__ __launch_bounds__(256) void attn_c3(const float* __restrict__ q3,
                                               const int* __restrict__ src,
                                               float* __restrict__ out) {
  const int gid = blockIdx.x * 256 + threadIdx.x;
  const int node = gid >> 4, r = gid & 15;
  const int j = src[node * 16 + r];
  const float* qn = q3 + node * 12;
  const float* kj = q3 + j * 12 + 3;
  float alpha = (qn[0] * kj[0] + qn[1] * kj[1] + qn[2] * kj[2]) *
                0.57735026918962576f;  // 1/sqrt(3)
  float m = alpha;
#pragma unroll
  for (int o = 8; o; o >>= 1) m = fmaxf(m, __shfl_xor(m, o, 16));
  const float e = __expf(alpha - m);
  float den = e;
#pragma unroll
  for (int o = 8; o; o >>= 1) den += __shfl_xor(den, o, 16);
  const float wgt = e / den;
  const float* vj = q3 + j * 12 + 6;
  float o0 = wgt * vj[0], o1 = wgt * vj[1], o2 = wgt * vj[2];
#pragma unroll
  for (int o = 8; o; o >>= 1) {
    o0 += __shfl_xor(o0, o, 16);
    o1 += __shfl_xor(o1, o, 16);
    o2 += __shfl_xor(o2, o, 16);
  }
  if (r == 0) {
    const float* sn = q3 + node * 12 + 9;
    out[node * 3 + 0] = o0 + sn[0];
    out[node * 3 + 1] = o1 + sn[1];
    out[node * 3 + 2] = o2 + sn[2];
  }
}

extern "C" void kernel_launch(void* const* d_in, const int* in_sizes, int n_in,
                              void* d_out, int out_size, void* d_ws,
                              size_t ws_size, hipStream_t stream) {
  const float* x = (const float*)d_in[1];
  const float* Wq1 = (const float*)d_in[2];
  const float* bq1 = (const float*)d_in[3];
  const float* Wk1 = (const float*)d_in[4];
  const float* bk1 = (const float*)d_in[5];
  const float* Wv1 = (const float*)d_in[6];
  const float* bv1 = (const float*)d_in[7];
  const float* Ws1 = (const float*)d_in[8];
  const float* bs1 = (const float*)d_in[9];
  const float* Wq2 = (const float*)d_in[10];
  const float* bq2 = (const float*)d_in[11];
  const float* Wk2 = (const float*)d_in[12];
  const float* bk2 = (const float*)d_in[13];
  const float* Wv2 = (const float*)d_in[14];
  const float* bv2 = (const float*)d_in[15];
  const float* Ws2 = (const float*)d_in[16];
  const float* bs2 = (const float*)d_in[17];
  const float* Wq3 = (const float*)d_in[18];
  const float* bq3 = (const float*)d_in[19];
  const float* Wk3 = (const float*)d_in[20];
  const float* bk3 = (const float*)d_in[21];
  const float* Wv3 = (const float*)d_in[22];
  const float* bv3 = (const float*)d_in[23];
  const float* Ws3 = (const float*)d_in[24];
  const float* bs3 = (const float*)d_in[25];

  const size_t MB = 1024 * 1024;
  const size_t KB = 1024;
  char* ws = (char*)d_ws;
  // knn build temporaries live in the qs region [0,16MB): dead until gemm1,
  // which runs strictly after knn_z on the same stream.
  float4* tmp4 = (float4*)(ws);                           // 256 KB
  float4* sorted4 = (float4*)(ws + 256 * KB);             // 256 KB
  int* sid = (int*)(ws + 512 * KB);                       // 64 KB
  int* sidx = (int*)(ws + 576 * KB);                      // 64 KB
  unsigned* hist = (unsigned*)(ws + 640 * KB);            // 512 B
  unsigned* slabstart = (unsigned*)(ws + 644 * KB);       // 516 B
  unsigned* slabfill = (unsigned*)(ws + 648 * KB);        // 512 B

  float* qs = (float*)(ws);                               // 16 MB (q|s fp32)
  unsigned short* kvh = (unsigned short*)(ws + 16 * MB);  // 8 MB (k|v bf16)
  float* h1 = (float*)(ws + 24 * MB);                     // 8 MB
  float* h2 = (float*)(ws + 32 * MB);                     // 8 MB
  int* src = (int*)(ws + 40 * MB);                        // 1 MB
  float* q3 = (float*)(ws + 42 * MB);                     // 768 KB
  float* out = (float*)d_out;

  hipMemsetAsync(hist, 0, NSLAB * sizeof(unsigned), stream);
  pack_slabs<<<NN / 256, 256, 0, stream>>>(x, tmp4, sid, hist);
  prefix_slabs<<<1, NSLAB, 0, stream>>>(hist, slabstart, slabfill);
  scatter_slabs<<<NN / 256, 256, 0, stream>>>(tmp4, sid, slabfill, sorted4,
                                              sidx);
  knn_z<<<NN / 4, 256, 0, stream>>>(sorted4, sidx, slabstart, src);
  gemm_qkvs<64><<<dim3(NN / 64, 8), 256, 0, stream>>>(
      x, Wq1, Wk1, Wv1, Ws1, bq1, bk1, bv1, bs1, qs, kvh);
  attn_c128<<<NN / 8, 256, 0, stream>>>(qs, kvh, src, nullptr, h1, 0);
  gemm_qkvs<128><<<dim3(NN / 64, 8), 256, 0, stream>>>(
      h1, Wq2, Wk2, Wv2, Ws2, bq2, bk2, bv2, bs2, qs, kvh);
  attn_c128<<<NN / 8, 256, 0, stream>>>(qs, kvh, src, h1, h2, 1);
  gemm_qkvs3<<<NN / 64, 256, 0, stream>>>(h2, Wq3, Wk3, Wv3, Ws3, bq3, bk3,
                                          bv3, bs3, q3);
  attn_c3<<<NN * 16 / 256, 256, 0, stream>>>(q3, src, out);
}

// Round 6
// 357.994 us; speedup vs baseline: 1.1934x; 1.0147x over previous
//
#include <hip/hip_runtime.h>
#include <math.h>

#define NN 16384
#define CAP 128    // per-query LDS candidate buffer (u64 keys)
#define WM 64      // shrink watermark; shrink inside push keeps cnt <= 127
#define KTOP 17    // keep top-17 (incl. self at dist~0), drop self at output
#define NSLAB 128  // z-slabs over [-4,4]
#define SH 0.0625f // slab width
#define SHI 16.0f  // 1/SH

typedef unsigned long long u64;

__device__ __forceinline__ int mbcnt64(u64 mask) {
  return __builtin_amdgcn_mbcnt_hi(
      (unsigned)(mask >> 32),
      __builtin_amdgcn_mbcnt_lo((unsigned)mask, 0));
}

// monotone float -> uint mapping (preserves total order incl. negatives)
__device__ __forceinline__ unsigned fmap(float d) {
  unsigned ub = __float_as_uint(d);
  return ub ^ ((unsigned)((int)ub >> 31) | 0x80000000u);
}

__device__ __forceinline__ float unfmap(unsigned ub) {
  unsigned fb = (ub & 0x80000000u) ? (ub ^ 0x80000000u) : ~ub;
  return __uint_as_float(fb);
}

// fp32 <-> bf16 (RNE, NaN-free data)
__device__ __forceinline__ unsigned short f2bf(float f) {
  unsigned u = __float_as_uint(f);
  return (unsigned short)((u + 0x7FFFu + ((u >> 16) & 1u)) >> 16);
}
__device__ __forceinline__ float bf2f(unsigned short h) {
  return __uint_as_float(((unsigned)h) << 16);
}

__device__ __forceinline__ u64 u64min(u64 a, u64 b) { return a < b ? a : b; }
__device__ __forceinline__ u64 u64max(u64 a, u64 b) { return a > b ? a : b; }

__device__ __forceinline__ int slabof(float v) {
  int c = (int)floorf((v + 4.0f) * SHI);
  return c < 0 ? 0 : (c > NSLAB - 1 ? NSLAB - 1 : c);
}

// bitonic sort of 64 u64 keys (1 reg/lane), ascending.
__device__ __forceinline__ void sort64(u64& r0, int lane) {
#pragma unroll
  for (int k = 2; k <= 64; k <<= 1) {
#pragma unroll
    for (int jj = k >> 1; jj >= 1; jj >>= 1) {
      const bool up = (lane & jj) == 0;
      const bool asc = (lane & k) == 0;
      u64 o = __shfl_xor(r0, jj);
      r0 = (up == asc) ? u64min(r0, o) : u64max(r0, o);
    }
  }
}

// radix-select shrink: p = KTOP-th smallest mapped key among buf[0..cnt),
// keep all entries with key <= p (ties kept -> exactness), compact to front.
// Key domain fmap(-L), monotone in d for fixed query. cq = L_kth: keep L >= cq.
__device__ __forceinline__ void radix_shrink(u64* buf, int& cnt, float& cq,
                                             int lane) {
  const u64 k0 = (lane < cnt) ? buf[lane] : ~0ull;
  const u64 k1 = (lane + 64 < cnt) ? buf[lane + 64] : ~0ull;
  const unsigned d0 = (unsigned)(k0 >> 32);
  const unsigned d1 = (unsigned)(k1 >> 32);
  unsigned p = 0u;
#pragma unroll
  for (int b = 31; b >= 0; --b) {
    const unsigned c = p | (1u << b);
    const u64 b0 = __ballot(d0 < c);
    const u64 b1 = __ballot(d1 < c);
    const int n = __popcll(b0) + __popcll(b1);
    if (n < KTOP) p = c;  // invariant: count(key < p) < KTOP
  }
  const bool v0 = d0 <= p;
  const bool v1 = d1 <= p;
  const u64 m0 = __ballot(v0);
  const u64 m1 = __ballot(v1);
  const int base = __popcll(m0);
  if (v0) buf[mbcnt64(m0)] = k0;
  if (v1) buf[base + mbcnt64(m1)] = k1;
  cnt = base + __popcll(m1);
  cq = -unfmap(p);
}

// ---------------- build: 128 z-slab counting sort ----------------
__global__ __launch_bounds__(256) void pack_slabs(const float* __restrict__ x,
                                                  float4* __restrict__ tmp4,
                                                  int* __restrict__ sid,
                                                  unsigned* __restrict__ hist) {
  const int i = blockIdx.x * 256 + threadIdx.x;
  const float a = x[i * 64 + 0];
  const float b = x[i * 64 + 1];
  const float c = x[i * 64 + 2];
  tmp4[i] = make_float4(a, b, c, -0.5f * (a * a + b * b + c * c));
  const int s = slabof(c);
  sid[i] = s;
  atomicAdd(&hist[s], 1u);
}

__global__ __launch_bounds__(128) void prefix_slabs(
    const unsigned* __restrict__ hist, unsigned* __restrict__ slabstart,
    unsigned* __restrict__ slabfill) {
  __shared__ unsigned ls[NSLAB];
  const int t = threadIdx.x;
  const unsigned h = hist[t];
  ls[t] = h;
  __syncthreads();
  for (int off = 1; off < NSLAB; off <<= 1) {
    const unsigned v = (t >= off) ? ls[t - off] : 0u;
    __syncthreads();
    ls[t] += v;
    __syncthreads();
  }
  const unsigned ex = ls[t] - h;  // exclusive
  slabstart[t] = ex;
  slabfill[t] = ex;
  if (t == NSLAB - 1) slabstart[NSLAB] = ls[t];  // = NN
}

__global__ __launch_bounds__(256) void scatter_slabs(
    const float4* __restrict__ tmp4, const int* __restrict__ sid,
    unsigned* __restrict__ slabfill, float4* __restrict__ sorted4,
    int* __restrict__ sidx) {
  const int i = blockIdx.x * 256 + threadIdx.x;
  const unsigned pos = atomicAdd(&slabfill[sid[i]], 1u);
  sorted4[pos] = tmp4[i];
  sidx[pos] = i;
}

// ---------------- kNN via z-slab WINDOW scan (r17) ----------------
// Wave handles 2 ADJACENT sorted queries (windows ~identical). Phase 1: one
// CONTIGUOUS run over slabs [slab(q0)-2, slab(q1)+2] (long run = amortized
// prologue -- r16's per-slab scan_run prologues were the regression). Then:
// shrink -> exact d17 -> required z-window -> scan only the extension ranges
// (contiguous, usually empty), iterate until stable. Slab edges are valid z
// lower bounds even under clamping. Inner body = proven brute step: 6 FMA +
// 2 cmp + 2 ballot for 2 queries, 1-deep prefetch, rare push, shrink at WM.
__global__ __launch_bounds__(256) void knn_z(
    const float4* __restrict__ sorted4, const int* __restrict__ sidx,
    const unsigned* __restrict__ slabstart, int* __restrict__ src) {
  __shared__ u64 bufs_[4][2][CAP];  // 8 KB
  const int lane = threadIdx.x & 63;
  const int wid = threadIdx.x >> 6;
  u64* buf0 = bufs_[wid][0];
  u64* buf1 = bufs_[wid][1];
  const int qpos = blockIdx.x * 8 + wid * 2;
  const float4 m0 = sorted4[qpos];
  const float4 m1 = sorted4[qpos + 1];
  const float qx0 = m0.x, qy0 = m0.y, qz0 = m0.z, q20 = -2.0f * m0.w;
  const float qx1 = m1.x, qy1 = m1.y, qz1 = m1.z, q21 = -2.0f * m1.w;
  float cq0 = -INFINITY, cq1 = -INFINITY;
  int cnt0 = 0, cnt1 = 0;

  auto scan_range = [&](int s, int e) {
    if (s >= e) return;
    int o = s;
    float4 p = sorted4[(s + lane) < e ? (s + lane) : s];
    while (o < e) {
      const int on = o + 64;
      float4 pn;
      if (on < e) {  // wave-uniform prefetch of next chunk
        const int jn = on + lane;
        pn = sorted4[jn < e ? jn : s];
      }
      const int j = o + lane;
      const bool in = j < e;
      const float L0 = fmaf(qx0, p.x, fmaf(qy0, p.y, fmaf(qz0, p.z, p.w)));
      const float L1 = fmaf(qx1, p.x, fmaf(qy1, p.y, fmaf(qz1, p.z, p.w)));
      const bool p0 = in && (L0 >= cq0);
      const bool p1 = in && (L1 >= cq1);
      const u64 mk0 = __ballot(p0);
      const u64 mk1 = __ballot(p1);
      if (mk0 | mk1) {
        if (mk0) {  // wave-uniform
          if (p0)
            buf0[cnt0 + mbcnt64(mk0)] =
                ((u64)fmap(-L0) << 32) | (unsigned)sidx[j];
          cnt0 += __popcll(mk0);
          if (cnt0 >= WM) radix_shrink(buf0, cnt0, cq0, lane);
        }
        if (mk1) {
          if (p1)
            buf1[cnt1 + mbcnt64(mk1)] =
                ((u64)fmap(-L1) << 32) | (unsigned)sidx[j];
          cnt1 += __popcll(mk1);
          if (cnt1 >= WM) radix_shrink(buf1, cnt1, cq1, lane);
        }
      }
      o = on;
      p = pn;
    }
  };

  // phase 1: one contiguous run over the initial +/-2-slab window
  int slo = slabof(qz0) - 2;
  if (slo < 0) slo = 0;
  int shi = slabof(qz1) + 2;
  if (shi > NSLAB - 1) shi = NSLAB - 1;
  scan_range((int)slabstart[slo], (int)slabstart[shi + 1]);

  const float zmin = fminf(qz0, qz1), zmax = fmaxf(qz0, qz1);
  while (true) {
    if (cnt0 >= KTOP) radix_shrink(buf0, cnt0, cq0, lane);
    if (cnt1 >= KTOP) radix_shrink(buf1, cnt1, cq1, lane);
    int rlo, rhi;
    if (cnt0 >= KTOP && cnt1 >= KTOP) {
      const float d0 = fmaxf(fmaf(-2.0f, cq0, q20), 0.0f);
      const float d1 = fmaxf(fmaf(-2.0f, cq1, q21), 0.0f);
      const float rneed = sqrtf(fmaxf(d0, d1) * 1.00002f + 1e-4f);
      rlo = (int)floorf((zmin - rneed + 4.0f) * SHI);
      rhi = (int)floorf((zmax + rneed + 4.0f) * SHI);
      if (rlo < 0) rlo = 0;
      if (rhi > NSLAB - 1) rhi = NSLAB - 1;
      if (rlo > slo) rlo = slo;  // window never shrinks
      if (rhi < shi) rhi = shi;
    } else {  // sparse tail: widen until both have KTOP candidates
      rlo = slo - 4;
      if (rlo < 0) rlo = 0;
      rhi = shi + 4;
      if (rhi > NSLAB - 1) rhi = NSLAB - 1;
    }
    bool ext = false;
    if (rlo < slo) {
      scan_range((int)slabstart[rlo], (int)slabstart[slo]);
      slo = rlo;
      ext = true;
    }
    if (rhi > shi) {
      scan_range((int)slabstart[shi + 1], (int)slabstart[rhi + 1]);
      shi = rhi;
      ext = true;
    }
    if (!ext) break;
  }

#pragma unroll 1
  for (int q = 0; q < 2; ++q) {
    u64* buf = q == 0 ? buf0 : buf1;
    int cnt = q == 0 ? cnt0 : cnt1;
    float cqd = q == 0 ? cq0 : cq1;
    if (cnt > 64) radix_shrink(buf, cnt, cqd, lane);  // tie pile-up guard
    const int qorig = sidx[qpos + q];
    u64 r0 = (lane < cnt) ? buf[lane] : ~0ull;
    sort64(r0, lane);
    const int idx = (int)(r0 & 0xFFFFFFFFull);
    const u64 selfm = __ballot((lane < KTOP) && (idx == qorig));
    const int sp = selfm ? (__ffsll((long long)selfm) - 1) : 99;
    const int outrank = lane - (lane > sp ? 1 : 0);
    if (lane < KTOP && lane != sp && outrank < 16)
      src[qorig * 16 + outrank] = idx;
  }
}

// ---------------- fused q|k|v|s GEMM: [N,KD] x 4x[KD,128] ----------
// q,s -> fp32 qs[node][256] (q: 0..127, s: 128..255)
// k,v -> bf16 kvh[node][256] (k: 0..127, v: 128..255) -- halves attn gathers
template <int KD>
__global__ __launch_bounds__(256) void gemm_qkvs(
    const float* __restrict__ X, const float* __restrict__ W0,
    const float* __restrict__ W1, const float* __restrict__ W2,
    const float* __restrict__ W3, const float* __restrict__ B0,
    const float* __restrict__ B1, const float* __restrict__ B2,
    const float* __restrict__ B3, float* __restrict__ qs,
    unsigned short* __restrict__ kvh) {
  __shared__ float As[64][68];  // [k][row], padded k-stride 68
  __shared__ float Bs[64][64];  // [k][col]
  const int brow = blockIdx.x * 64;
  const int by = blockIdx.y;          // 0..7 -> (matrix, half)
  const int wi = by >> 1;
  const float* W = wi == 0 ? W0 : wi == 1 ? W1 : wi == 2 ? W2 : W3;
  const float* bias = wi == 0 ? B0 : wi == 1 ? B1 : wi == 2 ? B2 : B3;
  const int cbase = (by & 1) * 64;
  const int tx = threadIdx.x & 15;   // col group (4 cols)
  const int ty = threadIdx.x >> 4;   // row group (4 rows)

  float acc[4][4] = {};
  for (int k0 = 0; k0 < KD; k0 += 64) {
    __syncthreads();
#pragma unroll
    for (int i = 0; i < 4; ++i) {  // stage A transposed: 64 rows x 64 k
      const int flat = threadIdx.x * 4 + i * 1024;
      const int r = flat >> 6, kk = flat & 63;
      const float4 v = *(const float4*)&X[(brow + r) * KD + k0 + kk];
      As[kk + 0][r] = v.x;
      As[kk + 1][r] = v.y;
      As[kk + 2][r] = v.z;
      As[kk + 3][r] = v.w;
    }
#pragma unroll
    for (int i = 0; i < 4; ++i) {  // stage B: 64 k x 64 cols
      const int flat = threadIdx.x * 4 + i * 1024;
      const int kk = flat >> 6, c = flat & 63;
      *(float4*)&Bs[kk][c] = *(const float4*)&W[(k0 + kk) * 128 + cbase + c];
    }
    __syncthreads();
#pragma unroll 8
    for (int k = 0; k < 64; ++k) {
      const float4 a = *(const float4*)&As[k][ty * 4];
      const float4 b = *(const float4*)&Bs[k][tx * 4];
      const float av[4] = {a.x, a.y, a.z, a.w};
      const float bv[4] = {b.x, b.y, b.z, b.w};
#pragma unroll
      for (int i = 0; i < 4; ++i)
#pragma unroll
        for (int jj = 0; jj < 4; ++jj)
          acc[i][jj] = fmaf(av[i], bv[jj], acc[i][jj]);
    }
  }
  const float4 bi = *(const float4*)&bias[cbase + tx * 4];
  const int col = cbase + tx * 4;
#pragma unroll
  for (int i = 0; i < 4; ++i) {
    const int row = brow + ty * 4 + i;
    float4 o;
    o.x = acc[i][0] + bi.x;
    o.y = acc[i][1] + bi.y;
    o.z = acc[i][2] + bi.z;
    o.w = acc[i][3] + bi.w;
    if (wi == 0) {
      *(float4*)&qs[row * 256 + col] = o;
    } else if (wi == 3) {
      *(float4*)&qs[row * 256 + 128 + col] = o;
    } else {
      ushort4 h;
      h.x = f2bf(o.x);
      h.y = f2bf(o.y);
      h.z = f2bf(o.z);
      h.w = f2bf(o.w);
      *(ushort4*)&kvh[row * 256 + (wi == 1 ? col : 128 + col)] = h;
    }
  }
}

// ---------------- attention, c=128: 32-lane group per node ----
__global__ __launch_bounds__(256) void attn_c128(
    const float* __restrict__ qs, const unsigned short* __restrict__ kvh,
    const int* __restrict__ src, const float* __restrict__ res,
    float* __restrict__ hout, int do_res) {
  const int g = threadIdx.x >> 5;  // 8 groups of 32 lanes per block
  const int node = blockIdx.x * 8 + g;
  const int c = threadIdx.x & 31;
  const float4 q4 = ((const float4*)(qs + node * 256))[c];

  int nb[16];
#pragma unroll
  for (int r = 0; r < 16; ++r) nb[r] = src[node * 16 + r];

  float p[16];
#pragma unroll
  for (int r = 0; r < 16; ++r) {
    const ushort4 k4 = ((const ushort4*)(kvh + nb[r] * 256))[c];
    p[r] = q4.x * bf2f(k4.x) + q4.y * bf2f(k4.y) + q4.z * bf2f(k4.z) +
           q4.w * bf2f(k4.w);
  }
#pragma unroll
  for (int o = 16; o; o >>= 1) {  // group-local (xor offsets < 32)
#pragma unroll
    for (int r = 0; r < 16; ++r) p[r] += __shfl_xor(p[r], o);
  }

  float m = p[0];
#pragma unroll
  for (int r = 1; r < 16; ++r) m = fmaxf(m, p[r]);
  float w[16];
  float den = 0.0f;
#pragma unroll
  for (int r = 0; r < 16; ++r) {
    w[r] = __expf((p[r] - m) * 0.088388347648318447f);  // 1/sqrt(128)
    den += w[r];
  }
  const float inv = 1.0f / den;
  float o0 = 0.0f, o1 = 0.0f, o2 = 0.0f, o3 = 0.0f;
#pragma unroll
  for (int r = 0; r < 16; ++r) {
    const ushort4 v4 = ((const ushort4*)(kvh + nb[r] * 256 + 128))[c];
    const float ww = w[r] * inv;
    o0 = fmaf(ww, bf2f(v4.x), o0);
    o1 = fmaf(ww, bf2f(v4.y), o1);
    o2 = fmaf(ww, bf2f(v4.z), o2);
    o3 = fmaf(ww, bf2f(v4.w), o3);
  }
  const float4 s4 = ((const float4*)(qs + node * 256 + 128))[c];
  float r0 = o0 + s4.x, r1 = o1 + s4.y, r2 = o2 + s4.z, r3 = o3 + s4.w;
  if (do_res) {
    const float4 h4 = ((const float4*)(res + node * 128))[c];
    r0 += h4.x;
    r1 += h4.y;
    r2 += h4.z;
    r3 += h4.w;
  }
  ((float4*)(hout + node * 128))[c] =
      make_float4(tanhf(r0), tanhf(r1), tanhf(r2), tanhf(r3));
}

// ---------------- layer 3 GEMM: [N,128] x 4x[128,3] -> [N,12] ----------------
__global__ __launch_bounds__(256) void gemm_qkvs3(
    const float* __restrict__ H, const float* __restrict__ W0,
    const float* __restrict__ W1, const float* __restrict__ W2,
    const float* __restrict__ W3, const float* __restrict__ B0,
    const float* __restrict__ B1, const float* __restrict__ B2,
    const float* __restrict__ B3, float* __restrict__ out) {
  __shared__ float hs[64][132];
  __shared__ float wsh[128 * 12];
  __shared__ float bsh[12];
  const int brow = blockIdx.x * 64;
  if (threadIdx.x < 12) {
    const int mi = threadIdx.x / 3, c = threadIdx.x % 3;
    const float* Bsel = mi == 0 ? B0 : mi == 1 ? B1 : mi == 2 ? B2 : B3;
    bsh[threadIdx.x] = Bsel[c];
  }
  for (int t = threadIdx.x; t < 1536; t += 256) {
    const int k = t / 12, cc = t % 12;
    const int mi = cc / 3, c = cc % 3;
    const float* Wsel = mi == 0 ? W0 : mi == 1 ? W1 : mi == 2 ? W2 : W3;
    wsh[t] = Wsel[k * 3 + c];
  }
#pragma unroll
  for (int i = 0; i < 8; ++i) {
    const int flat = threadIdx.x * 4 + i * 1024;
    const int r = flat >> 7, kk = flat & 127;
    *(float4*)&hs[r][kk] = *(const float4*)&H[(brow + r) * 128 + kk];
  }
  __syncthreads();
  const int r = threadIdx.x >> 2;
  const int part = threadIdx.x & 3;
  float a0 = 0.0f, a1 = 0.0f, a2 = 0.0f;
#pragma unroll 4
  for (int k = 0; k < 128; ++k) {
    const float h = hs[r][k];
    a0 = fmaf(h, wsh[k * 12 + part * 3 + 0], a0);
    a1 = fmaf(h, wsh[k * 12 + part * 3 + 1], a1);
    a2 = fmaf(h, wsh[k * 12 + part * 3 + 2], a2);
  }
  const int row = brow + r;
  out[row * 12 + part * 3 + 0] = a0 + bsh[part * 3 + 0];
  out[row * 12 + part * 3 + 1] = a1 + bsh[part * 3 + 1];
  out[row * 12 + part * 3 + 2] = a2 + bsh[part * 3 + 2];
}

// ---------------- attention, c=3: 16 lanes per node ----------------
__global__ __launch_bounds__(256) void attn_c3(const float* __restrict__ q3,
                                               const int* __restrict__ src,
                                               float* __restrict__ out) {
  const int gid = blockIdx.x * 256 + threadIdx.x;
  const int node = gid >> 4, r = gid & 15;
  const int j = src[node * 16 + r];
  const float* qn = q3 + node * 12;
  const float* kj = q3 + j * 12 + 3;
  float alpha = (qn[0] * kj[0] + qn[1] * kj[1] + qn[2] * kj[2]) *
                0.57735026918962576f;  // 1/sqrt(3)
  float m = alpha;
#pragma unroll
  for (int o = 8; o; o >>= 1) m = fmaxf(m, __shfl_xor(m, o, 16));
  const float e = __expf(alpha - m);
  float den = e;
#pragma unroll
  for (int o = 8; o; o >>= 1) den += __shfl_xor(den, o, 16);
  const float wgt = e / den;
  const float* vj = q3 + j * 12 + 6;
  float o0 = wgt * vj[0], o1 = wgt * vj[1], o2 = wgt * vj[2];
#pragma unroll
  for (int o = 8; o; o >>= 1) {
    o0 += __shfl_xor(o0, o, 16);
    o1 += __shfl_xor(o1, o, 16);
    o2 += __shfl_xor(o2, o, 16);
  }
  if (r == 0) {
    const float* sn = q3 + node * 12 + 9;
    out[node * 3 + 0] = o0 + sn[0];
    out[node * 3 + 1] = o1 + sn[1];
    out[node * 3 + 2] = o2 + sn[2];
  }
}

extern "C" void kernel_launch(void* const* d_in, const int* in_sizes, int n_in,
                              void* d_out, int out_size, void* d_ws,
                              size_t ws_size, hipStream_t stream) {
  const float* x = (const float*)d_in[1];
  const float* Wq1 = (const float*)d_in[2];
  const float* bq1 = (const float*)d_in[3];
  const float* Wk1 = (const float*)d_in[4];
  const float* bk1 = (const float*)d_in[5];
  const float* Wv1 = (const float*)d_in[6];
  const float* bv1 = (const float*)d_in[7];
  const float* Ws1 = (const float*)d_in[8];
  const float* bs1 = (const float*)d_in[9];
  const float* Wq2 = (const float*)d_in[10];
  const float* bq2 = (const float*)d_in[11];
  const float* Wk2 = (const float*)d_in[12];
  const float* bk2 = (const float*)d_in[13];
  const float* Wv2 = (const float*)d_in[14];
  const float* bv2 = (const float*)d_in[15];
  const float* Ws2 = (const float*)d_in[16];
  const float* bs2 = (const float*)d_in[17];
  const float* Wq3 = (const float*)d_in[18];
  const float* bq3 = (const float*)d_in[19];
  const float* Wk3 = (const float*)d_in[20];
  const float* bk3 = (const float*)d_in[21];
  const float* Wv3 = (const float*)d_in[22];
  const float* bv3 = (const float*)d_in[23];
  const float* Ws3 = (const float*)d_in[24];
  const float* bs3 = (const float*)d_in[25];

  const size_t MB = 1024 * 1024;
  const size_t KB = 1024;
  char* ws = (char*)d_ws;
  // knn build temporaries live in the qs region [0,16MB): dead until gemm1,
  // which runs strictly after knn_z on the same stream.
  float4* tmp4 = (float4*)(ws);                           // 256 KB
  float4* sorted4 = (float4*)(ws + 256 * KB);             // 256 KB
  int* sid = (int*)(ws + 512 * KB);                       // 64 KB
  int* sidx = (int*)(ws + 576 * KB);                      // 64 KB
  unsigned* hist = (unsigned*)(ws + 640 * KB);            // 512 B
  unsigned* slabstart = (unsigned*)(ws + 644 * KB);       // 516 B
  unsigned* slabfill = (unsigned*)(ws + 648 * KB);        // 512 B

  float* qs = (float*)(ws);                               // 16 MB (q|s fp32)
  unsigned short* kvh = (unsigned short*)(ws + 16 * MB);  // 8 MB (k|v bf16)
  float* h1 = (float*)(ws + 24 * MB);                     // 8 MB
  float* h2 = (float*)(ws + 32 * MB);                     // 8 MB
  int* src = (int*)(ws + 40 * MB);                        // 1 MB
  float* q3 = (float*)(ws + 42 * MB);                     // 768 KB
  float* out = (float*)d_out;

  hipMemsetAsync(hist, 0, NSLAB * sizeof(unsigned), stream);
  pack_slabs<<<NN / 256, 256, 0, stream>>>(x, tmp4, sid, hist);
  prefix_slabs<<<1, NSLAB, 0, stream>>>(hist, slabstart, slabfill);
  scatter_slabs<<<NN / 256, 256, 0, stream>>>(tmp4, sid, slabfill, sorted4,
                                              sidx);
  knn_z<<<NN / 8, 256, 0, stream>>>(sorted4, sidx, slabstart, src);
  gemm_qkvs<64><<<dim3(NN / 64, 8), 256, 0, stream>>>(
      x, Wq1, Wk1, Wv1, Ws1, bq1, bk1, bv1, bs1, qs, kvh);
  attn_c128<<<NN / 8, 256, 0, stream>>>(qs, kvh, src, nullptr, h1, 0);
  gemm_qkvs<128><<<dim3(NN / 64, 8), 256, 0, stream>>>(
      h1, Wq2, Wk2, Wv2, Ws2, bq2, bk2, bv2, bs2, qs, kvh);
  attn_c128<<<NN / 8, 256, 0, stream>>>(qs, kvh, src, h1, h2, 1);
  gemm_qkvs3<<<NN / 64, 256, 0, stream>>>(h2, Wq3, Wk3, Wv3, Ws3, bq3, bk3,
                                          bv3, bs3, q3);
  attn_c3<<<NN * 16 / 256, 256, 0, stream>>>(q3, src, out);
}